// Round 5
// baseline (426.913 us; speedup 1.0000x reference)
//
#include <hip/hip_runtime.h>
#include <hip/hip_bf16.h>
#include <hip/hip_cooperative_groups.h>
#include <cstddef>

namespace cg = cooperative_groups;

// ---------------------------------------------------------------------------
// LinearAttention — round 5: single cooperative kernel.
//
// P0  pack Wk/Wv -> LDS (per-block, redundant) ; rmsnorm block's 256 tokens
//     -> LDS xbuf (bf16, row pad 136 shorts => 2-way-free bank pattern)
// P1  kv GEMMs (weights via ds_read) + exp + in-register context, atomic
//     drain -> cred -> CpAll[bid]                     (math verbatim r3/r4)
// P2a tree-reduce CpAll -> Cpp ; pack Wq -> LDS       (grid.sync around)
// P2b + mem-kv terms -> ctxN (numerator) / Sden
// P2c W2 fold (divide folded) -> W2p global
// P3  q GEMM reusing P1's xf REGISTERS (same frag layout as A and B),
//     softmax, W2 GEMM (LDS), bias + rmsnorm -> y     (math verbatim r4 k5)
//
// x read once (33.5 MB), y written once (33.5 MB), CpAll round trip 8.6 MB.
// ---------------------------------------------------------------------------

typedef __attribute__((ext_vector_type(8))) short short8;
typedef __attribute__((ext_vector_type(4))) float f32x4;

static constexpr int   NTOK = 65536;                        // H*W
static constexpr float NORM_SCALE_F = 11.313708498984761f;  // sqrt(128)
static constexpr float SCALE_F      = 0.17677669529663687f; // 1/sqrt(32)

__device__ __forceinline__ unsigned short f2bf(float f) {
  __hip_bfloat16 h = __float2bfloat16(f);
  return *reinterpret_cast<unsigned short*>(&h);
}
__device__ __forceinline__ short sbf(float f) { return (short)f2bf(f); }

#define MFMA16(A, B, C) __builtin_amdgcn_mfma_f32_16x16x32_bf16((A), (B), (C), 0, 0, 0)

__global__ __launch_bounds__(512, 2) void k_all(
    const float* __restrict__ x, const float* __restrict__ gamma1,
    const float* __restrict__ w_qkv, const float* __restrict__ mem_kv,
    const float* __restrict__ w_out, const float* __restrict__ b_out,
    const float* __restrict__ gamma2, float* __restrict__ y,
    float* __restrict__ CpAll, float* __restrict__ Cpp,
    float* __restrict__ ctxN, unsigned short* __restrict__ W2p) {
  __shared__ unsigned short xbuf[256 * 136];  // 68 KB: normalized x, bf16
  __shared__ unsigned short wbuf[32768];      // 64 KB: P1 Wk|Wv ; P2+ Wq|W2p
  __shared__ float cred[4224];                // 16.5 KB: block context partial

  cg::grid_group grid = cg::this_grid();

  const int tid = threadIdx.x, bid = blockIdx.x;
  const int wv = tid >> 6, ln = tid & 63;
  const int g4 = ln >> 4, t16 = ln & 15;
  const int tok0 = bid * 256;

  // ---------------- P0a: pack Wk (wbuf[0..16384)) and Wv (wbuf[16384..32768))
  #pragma unroll
  for (int g = 0; g < 8; ++g) {
    const int gi = tid * 8 + g;          // 0..4095 frag-groups of 8 elems
    const int m = 1 + (gi >> 11);        // 1 = k rows, 2 = v rows of w_qkv
    const int gg = gi & 2047;
    const int lnp = gg & 63, frag = gg >> 6;
    const int ks = frag & 3, rt = frag >> 2;
    const int row = rt * 16 + (lnp & 15);
    const int cb = ks * 32 + (lnp >> 4) * 8;
    short8 o;
    #pragma unroll
    for (int j = 0; j < 8; ++j)
      o[j] = sbf(w_qkv[(m * 128 + row) * 128 + cb + j] * (gamma1[cb + j] + 1.0f) * NORM_SCALE_F);
    *reinterpret_cast<short8*>(&wbuf[gi * 8]) = o;
  }

  // ---------------- P0b: rmsnorm block's 256 tokens -> xbuf
  #pragma unroll
  for (int it = 0; it < 2; ++it) {
    const int j = it * 512 + tid;        // 0..1023 = 256 tok x 4 ch-groups
    const int tl = j >> 2;
    const int cgs = (j & 3) * 32;
    float v[32];
    float sq = 0.f;
    #pragma unroll
    for (int jj = 0; jj < 32; ++jj) {
      v[jj] = x[(size_t)(cgs + jj) * NTOK + tok0 + tl];
      sq += v[jj] * v[jj];
    }
    sq += __shfl_xor(sq, 1, 64);
    sq += __shfl_xor(sq, 2, 64);
    const float s = rsqrtf(sq);
    #pragma unroll
    for (int g = 0; g < 4; ++g) {
      short8 o;
      #pragma unroll
      for (int jj = 0; jj < 8; ++jj) o[jj] = sbf(v[g * 8 + jj] * s);
      *reinterpret_cast<short8*>(&xbuf[tl * 136 + cgs + g * 8]) = o;
    }
  }
  for (int i = tid; i < 4224; i += 512) cred[i] = 0.f;
  __syncthreads();

  // ---------------- P1: kv GEMMs + context (wave owns 32 tokens)
  short8 xf[2][4];   // survives to P3 (xbuf stays intact as spill backstop)
  #pragma unroll
  for (int tg = 0; tg < 2; ++tg)
    #pragma unroll
    for (int ks = 0; ks < 4; ++ks)
      xf[tg][ks] = *reinterpret_cast<const short8*>(
          &xbuf[(wv * 32 + tg * 16 + t16) * 136 + ks * 32 + g4 * 8]);

  {
    f32x4 cacc[4][2][2] = {};
    float sacc[4][2] = {};
    #pragma unroll
    for (int h = 0; h < 4; ++h) {
      // k^T GEMM (A = x^T frags, B = Wk frags from LDS)
      f32x4 ka[2][2] = {};
      #pragma unroll
      for (int ks = 0; ks < 4; ++ks) {
        const short8 b0 = *reinterpret_cast<const short8*>(&wbuf[(((2 * h + 0) * 4 + ks) * 64 + ln) * 8]);
        const short8 b1 = *reinterpret_cast<const short8*>(&wbuf[(((2 * h + 1) * 4 + ks) * 64 + ln) * 8]);
        #pragma unroll
        for (int tg = 0; tg < 2; ++tg) {
          ka[0][tg] = MFMA16(xf[tg][ks], b0, ka[0][tg]);
          ka[1][tg] = MFMA16(xf[tg][ks], b1, ka[1][tg]);
        }
      }
      // exp -> paired A-frag, S partial in registers
      short8 keA[2];
      #pragma unroll
      for (int mt = 0; mt < 2; ++mt) {
        float sl = 0.f;
        short8 u;
        #pragma unroll
        for (int tg = 0; tg < 2; ++tg)
          #pragma unroll
          for (int r = 0; r < 4; ++r) {
            const float e = __expf(ka[mt][tg][r]);
            sl += e;
            u[tg * 4 + r] = sbf(e);
          }
        keA[mt] = u;
        sacc[h][mt] += sl;
      }
      // v^T GEMM
      f32x4 va[2][2] = {};
      #pragma unroll
      for (int ks = 0; ks < 4; ++ks) {
        const short8 b0 = *reinterpret_cast<const short8*>(&wbuf[16384 + (((2 * h + 0) * 4 + ks) * 64 + ln) * 8]);
        const short8 b1 = *reinterpret_cast<const short8*>(&wbuf[16384 + (((2 * h + 1) * 4 + ks) * 64 + ln) * 8]);
        #pragma unroll
        for (int tg = 0; tg < 2; ++tg) {
          va[0][tg] = MFMA16(xf[tg][ks], b0, va[0][tg]);
          va[1][tg] = MFMA16(xf[tg][ks], b1, va[1][tg]);
        }
      }
      short8 vB[2];
      #pragma unroll
      for (int et = 0; et < 2; ++et) {
        short8 u;
        #pragma unroll
        for (int tg = 0; tg < 2; ++tg)
          #pragma unroll
          for (int r = 0; r < 4; ++r)
            u[tg * 4 + r] = sbf(va[et][tg][r]);
        vB[et] = u;
      }
      // context MFMA, register accumulate
      #pragma unroll
      for (int dt = 0; dt < 2; ++dt)
        #pragma unroll
        for (int et = 0; et < 2; ++et)
          cacc[h][dt][et] = MFMA16(keA[dt], vB[et], cacc[h][dt][et]);
    }
    // drain to block partial
    #pragma unroll
    for (int h = 0; h < 4; ++h)
      #pragma unroll
      for (int dt = 0; dt < 2; ++dt)
        #pragma unroll
        for (int et = 0; et < 2; ++et)
          #pragma unroll
          for (int r = 0; r < 4; ++r)
            atomicAdd(&cred[h * 1024 + (dt * 16 + g4 * 4 + r) * 32 + et * 16 + t16],
                      cacc[h][dt][et][r]);
    #pragma unroll
    for (int h = 0; h < 4; ++h)
      #pragma unroll
      for (int mt = 0; mt < 2; ++mt) {
        float sl = sacc[h][mt];
        sl += __shfl_xor(sl, 16, 64);
        sl += __shfl_xor(sl, 32, 64);
        if (g4 == 0) atomicAdd(&cred[4096 + h * 32 + mt * 16 + t16], sl);
      }
  }
  __syncthreads();
  for (int i = tid; i < 4224; i += 512)
    CpAll[(size_t)bid * 4224 + i] = cred[i];
  __threadfence();
  grid.sync();

  // ---------------- P2a: tree-reduce 256 partials -> Cpp[8][4224]; pack Wq
  const int gid = bid * 512 + tid;
  if (gid < 33792) {
    const unsigned chunk = (unsigned)gid / 4224u;
    const unsigned e = (unsigned)gid - chunk * 4224u;
    float s = 0.f;
    #pragma unroll 4
    for (int bb = 0; bb < 32; ++bb)
      s += CpAll[(size_t)(chunk * 32 + bb) * 4224 + e];
    Cpp[chunk * 4224 + e] = s;
  }
  #pragma unroll
  for (int g = 0; g < 4; ++g) {          // Wq -> wbuf[0..16384) (overwrites Wk)
    const int gi = tid * 4 + g;          // 0..2047
    const int lnp = gi & 63, frag = gi >> 6;
    const int ks = frag & 3, rt = frag >> 2;
    const int row = rt * 16 + (lnp & 15);
    const int cb = ks * 32 + (lnp >> 4) * 8;
    short8 o;
    #pragma unroll
    for (int j = 0; j < 8; ++j)
      o[j] = sbf(w_qkv[row * 128 + cb + j] * (gamma1[cb + j] + 1.0f) * NORM_SCALE_F);
    *reinterpret_cast<short8*>(&wbuf[gi * 8]) = o;
  }
  __threadfence();
  grid.sync();

  // ---------------- P2b: final reduce + mem-kv terms -> ctxN / Sden
  if (gid < 4224) {
    float s = 0.f;
    #pragma unroll
    for (int c = 0; c < 8; ++c) s += Cpp[c * 4224 + gid];
    if (gid < 4096) {
      const int hh = gid >> 10, d = (gid >> 5) & 31, ev = gid & 31;
      #pragma unroll
      for (int m = 0; m < 4; ++m)
        s += __expf(mem_kv[(hh * 32 + d) * 4 + m]) * mem_kv[512 + (hh * 32 + ev) * 4 + m];
    } else {
      const int si = gid - 4096;
      const int hh = si >> 5, d = si & 31;
      #pragma unroll
      for (int m = 0; m < 4; ++m) s += __expf(mem_kv[(hh * 32 + d) * 4 + m]);
    }
    ctxN[gid] = s;
  }
  __threadfence();
  grid.sync();

  // ---------------- P2c: W2 fold (divide folded in) -> W2p global
  if (gid < 2048) {
    const int base = gid * 8;
    const int ln2 = gid & 63, frag = gid >> 6;
    const int h = frag & 3, ot = frag >> 2;
    const int o = ot * 16 + (ln2 & 15);
    float wrow[32];
    #pragma unroll
    for (int e = 0; e < 32; ++e) wrow[e] = w_out[o * 128 + h * 32 + e];
    short8 o8;
    #pragma unroll
    for (int j = 0; j < 8; ++j) {
      const int d = (j >> 2) * 16 + ((ln2 >> 4) << 2) + (j & 3);
      float s = 0.f;
      #pragma unroll
      for (int e = 0; e < 32; ++e)
        s += wrow[e] * ctxN[h * 1024 + d * 32 + e];
      o8[j] = sbf(s / ctxN[4096 + h * 32 + d] * SCALE_F);
    }
    *reinterpret_cast<short8*>(&W2p[base]) = o8;
  }
  __threadfence();
  grid.sync();

  // ---------------- P3: stage W2p -> LDS; q GEMM (register xf) -> softmax
  //                  -> W2 GEMM -> bias + rmsnorm -> y
  #pragma unroll
  for (int g = 0; g < 4; ++g) {
    const int i8 = (tid * 4 + g) * 8;
    *reinterpret_cast<short8*>(&wbuf[16384 + i8]) =
        *reinterpret_cast<const short8*>(&W2p[i8]);
  }
  __syncthreads();

  const int n0 = tok0 + wv * 32;
  short8 qB[4][2];
  #pragma unroll
  for (int h = 0; h < 4; ++h) {
    f32x4 qa[2][2] = {};   // lane: hd = h*32 + rtl*16 + g4*4 + r, tok = tg*16+t16
    #pragma unroll
    for (int ks = 0; ks < 4; ++ks) {
      const short8 a0 = *reinterpret_cast<const short8*>(&wbuf[(((2 * h + 0) * 4 + ks) * 64 + ln) * 8]);
      const short8 a1 = *reinterpret_cast<const short8*>(&wbuf[(((2 * h + 1) * 4 + ks) * 64 + ln) * 8]);
      #pragma unroll
      for (int tg = 0; tg < 2; ++tg) {
        qa[0][tg] = MFMA16(a0, xf[tg][ks], qa[0][tg]);
        qa[1][tg] = MFMA16(a1, xf[tg][ks], qa[1][tg]);
      }
    }
    #pragma unroll
    for (int tg = 0; tg < 2; ++tg) {
      float ev[2][4];
      float ss = 0.f;
      #pragma unroll
      for (int rtl = 0; rtl < 2; ++rtl)
        #pragma unroll
        for (int r = 0; r < 4; ++r) {
          ev[rtl][r] = __expf(qa[rtl][tg][r]);
          ss += ev[rtl][r];
        }
      ss += __shfl_xor(ss, 16, 64);
      ss += __shfl_xor(ss, 32, 64);
      const float inv = 1.0f / ss;
      short8 u;
      #pragma unroll
      for (int rtl = 0; rtl < 2; ++rtl)
        #pragma unroll
        for (int r = 0; r < 4; ++r)
          u[rtl * 4 + r] = sbf(ev[rtl][r] * inv);
      qB[h][tg] = u;   // B-frag slot j: hd = h*32 + (j>>2)*16 + g4*4 + (j&3)
    }
  }

  f32x4 z[8][2] = {};
  #pragma unroll
  for (int h = 0; h < 4; ++h)
    #pragma unroll
    for (int ot = 0; ot < 8; ++ot) {
      const short8 a = *reinterpret_cast<const short8*>(&wbuf[16384 + ((ot * 4 + h) * 64 + ln) * 8]);
      #pragma unroll
      for (int tg = 0; tg < 2; ++tg)
        z[ot][tg] = MFMA16(a, qB[h][tg], z[ot][tg]);
    }

  float ssq[2] = {0.f, 0.f};
  #pragma unroll
  for (int ot = 0; ot < 8; ++ot) {
    const float4 bb = *reinterpret_cast<const float4*>(b_out + ot * 16 + g4 * 4);
    const float barr[4] = {bb.x, bb.y, bb.z, bb.w};
    #pragma unroll
    for (int tg = 0; tg < 2; ++tg)
      #pragma unroll
      for (int r = 0; r < 4; ++r) {
        const float zb = z[ot][tg][r] + barr[r];
        z[ot][tg][r] = zb;
        ssq[tg] += zb * zb;
      }
  }
  float rr[2];
  #pragma unroll
  for (int tg = 0; tg < 2; ++tg) {
    float s = ssq[tg];
    s += __shfl_xor(s, 16, 64);
    s += __shfl_xor(s, 32, 64);
    rr[tg] = rsqrtf(s);
  }
  #pragma unroll
  for (int ot = 0; ot < 8; ++ot) {
    const float4 gg = *reinterpret_cast<const float4*>(gamma2 + ot * 16 + g4 * 4);
    const float garr[4] = {gg.x, gg.y, gg.z, gg.w};
    #pragma unroll
    for (int tg = 0; tg < 2; ++tg)
      #pragma unroll
      for (int r = 0; r < 4; ++r) {
        const int row = ot * 16 + g4 * 4 + r;
        y[(size_t)row * NTOK + n0 + tg * 16 + t16] =
            z[ot][tg][r] * rr[tg] * (garr[r] + 1.0f) * NORM_SCALE_F;
      }
  }
}

// ---------------------------------------------------------------------------
extern "C" void kernel_launch(void* const* d_in, const int* in_sizes, int n_in,
                              void* d_out, int out_size, void* d_ws, size_t ws_size,
                              hipStream_t stream) {
  const float* x      = (const float*)d_in[0];
  const float* gamma1 = (const float*)d_in[1];
  const float* w_qkv  = (const float*)d_in[2];
  const float* mem_kv = (const float*)d_in[3];
  const float* w_out  = (const float*)d_in[4];
  const float* b_out  = (const float*)d_in[5];
  const float* gamma2 = (const float*)d_in[6];
  float* out = (float*)d_out;
  float* ws  = (float*)d_ws;

  // ws layout (float slots), total ~4.5 MB:
  float* CpAll = ws;                         // 256*4224 = 1081344
  float* Cpp   = CpAll + 1081344;            // 8*4224   = 33792
  float* ctxN  = Cpp + 33792;                // 4224
  unsigned short* W2p = (unsigned short*)(ctxN + 4224);  // 16384 ushorts

  void* args[] = {(void*)&x, (void*)&gamma1, (void*)&w_qkv, (void*)&mem_kv,
                  (void*)&w_out, (void*)&b_out, (void*)&gamma2, (void*)&out,
                  (void*)&CpAll, (void*)&Cpp, (void*)&ctxN, (void*)&W2p};
  hipLaunchCooperativeKernel((const void*)k_all, dim3(256), dim3(512), args, 0, stream);
}

// Round 6
// 180.400 us; speedup vs baseline: 2.3665x; 2.3665x over previous
//
#include <hip/hip_runtime.h>
#include <hip/hip_bf16.h>
#include <cstddef>

// ---------------------------------------------------------------------------
// LinearAttention — round 6: multi-kernel pipeline, ROLLED head loops.
//
// Hypothesis from r2-r5 counters: the ~50us k1/k5 kernels are I-fetch bound
// (fully-unrolled one-shot code, every counter <6%). Fix: #pragma unroll 1 on
// the per-head loop so the code is ~4x smaller and hot after iteration 1.
// Pipeline: K0 norm+pack (fused) -> K1 kv+context -> K2 partial reduce ->
// K3 ctx+W2 fold (fused) -> K4 q+softmax+out. All math verbatim r4/r5.
// ---------------------------------------------------------------------------

typedef __attribute__((ext_vector_type(8))) short short8;
typedef __attribute__((ext_vector_type(4))) float f32x4;

static constexpr int   NTOK = 65536;                        // H*W
static constexpr float NORM_SCALE_F = 11.313708498984761f;  // sqrt(128)
static constexpr float SCALE_F      = 0.17677669529663687f; // 1/sqrt(32)

__device__ __forceinline__ unsigned short f2bf(float f) {
  __hip_bfloat16 h = __float2bfloat16(f);
  return *reinterpret_cast<unsigned short*>(&h);
}
__device__ __forceinline__ short sbf(float f) { return (short)f2bf(f); }

#define MFMA16(A, B, C) __builtin_amdgcn_mfma_f32_16x16x32_bf16((A), (B), (C), 0, 0, 0)

// ---------------------------------------------------------------- K0:
// blocks [0,1024): xn[tok][c] = bf16(x * rsqrt(sum_c x^2)) (r4 k_norm verbatim)
// blocks 1024..1026: pack w_qkv matrix m=bid-1024 frag-linear into Wall
__global__ __launch_bounds__(256) void k0_norm_pack(const float* __restrict__ x,
                                                    const float* __restrict__ w_qkv,
                                                    const float* __restrict__ gamma1,
                                                    unsigned short* __restrict__ xn,
                                                    unsigned short* __restrict__ Wall) {
  const int t = threadIdx.x, bid = blockIdx.x;
  if (bid < 1024) {
    const int tok = bid * 64 + (t >> 2);
    const int cg = (t & 3) * 32;
    float v[32];
    float sq = 0.f;
    #pragma unroll
    for (int j = 0; j < 32; ++j) {
      v[j] = x[(size_t)(cg + j) * NTOK + tok];
      sq += v[j] * v[j];
    }
    sq += __shfl_xor(sq, 1, 64);
    sq += __shfl_xor(sq, 2, 64);
    const float s = rsqrtf(sq);
    #pragma unroll
    for (int g = 0; g < 4; ++g) {
      short8 o;
      #pragma unroll
      for (int j = 0; j < 8; ++j) o[j] = sbf(v[g * 8 + j] * s);
      *reinterpret_cast<short8*>(xn + (size_t)tok * 128 + cg + g * 8) = o;
    }
  } else {
    const int m = bid - 1024;           // 0=q, 1=k, 2=v
    #pragma unroll
    for (int g = 0; g < 8; ++g) {
      const int gi = t * 8 + g;         // 0..2047 short8 groups
      const int lnp = gi & 63, frag = gi >> 6;
      const int ks = frag & 3, rt = frag >> 2;
      const int row = rt * 16 + (lnp & 15);
      const int cb = ks * 32 + (lnp >> 4) * 8;
      short8 o;
      #pragma unroll
      for (int j = 0; j < 8; ++j)
        o[j] = sbf(w_qkv[(m * 128 + row) * 128 + cb + j] * (gamma1[cb + j] + 1.0f) * NORM_SCALE_F);
      *reinterpret_cast<short8*>(Wall + m * 16384 + gi * 8) = o;
    }
  }
}

// ---------------------------------------------------------------- K1:
// 256 blocks x 512 threads (8 waves); wave owns 32 tokens. ROLLED h-loop.
// Per head: k^T GEMM -> exp -> paired A-frag; v^T GEMM -> paired B-frag;
// context MFMA -> LDS atomic drain. Then block partial -> CpAll[bid].
__global__ __launch_bounds__(512) void k1_kv(const unsigned short* __restrict__ xn,
                                             const unsigned short* __restrict__ Wkp,
                                             const unsigned short* __restrict__ Wvp,
                                             float* __restrict__ CpAll) {
  __shared__ float cred[4224];     // [0,4096): C[h][d][e]; [4096,4224): S[h][d]
  const int tid = threadIdx.x, wv = tid >> 6, ln = tid & 63;
  const int g4 = ln >> 4, t16 = ln & 15;
  const int n0 = (blockIdx.x * 8 + wv) * 32;

  for (int i = tid; i < 4224; i += 512) cred[i] = 0.f;
  __syncthreads();

  // x^T A-frags (lane: token = tg*16+t16, c = ks*32+g4*8+j)
  short8 xf[2][4];
  #pragma unroll
  for (int tg = 0; tg < 2; ++tg)
    #pragma unroll
    for (int ks = 0; ks < 4; ++ks)
      xf[tg][ks] = *reinterpret_cast<const short8*>(
          xn + (size_t)(n0 + tg * 16 + t16) * 128 + ks * 32 + g4 * 8);

  #pragma unroll 1
  for (int h = 0; h < 4; ++h) {
    const unsigned short* wk = Wkp + h * 4096;
    const unsigned short* wvp = Wvp + h * 4096;
    // k^T GEMM: D[token][d]  (A = x^T, B = Wk)
    f32x4 ka[2][2] = {};   // [mt][tg]
    #pragma unroll
    for (int ks = 0; ks < 4; ++ks) {
      const short8 b0 = *reinterpret_cast<const short8*>(wk + ks * 512 + ln * 8);
      const short8 b1 = *reinterpret_cast<const short8*>(wk + 2048 + ks * 512 + ln * 8);
      #pragma unroll
      for (int tg = 0; tg < 2; ++tg) {
        ka[0][tg] = MFMA16(xf[tg][ks], b0, ka[0][tg]);
        ka[1][tg] = MFMA16(xf[tg][ks], b1, ka[1][tg]);
      }
    }
    // exp -> paired A-frag (j = tg*4+r), S partial -> LDS atomic
    short8 keA[2];
    #pragma unroll
    for (int mt = 0; mt < 2; ++mt) {
      float sl = 0.f;
      short8 u;
      #pragma unroll
      for (int tg = 0; tg < 2; ++tg)
        #pragma unroll
        for (int r = 0; r < 4; ++r) {
          const float e = __expf(ka[mt][tg][r]);
          sl += e;
          u[tg * 4 + r] = sbf(e);
        }
      keA[mt] = u;
      sl += __shfl_xor(sl, 16, 64);
      sl += __shfl_xor(sl, 32, 64);
      if (g4 == 0) atomicAdd(&cred[4096 + h * 32 + mt * 16 + t16], sl);
    }
    // v^T GEMM
    f32x4 va[2][2] = {};
    #pragma unroll
    for (int ks = 0; ks < 4; ++ks) {
      const short8 b0 = *reinterpret_cast<const short8*>(wvp + ks * 512 + ln * 8);
      const short8 b1 = *reinterpret_cast<const short8*>(wvp + 2048 + ks * 512 + ln * 8);
      #pragma unroll
      for (int tg = 0; tg < 2; ++tg) {
        va[0][tg] = MFMA16(xf[tg][ks], b0, va[0][tg]);
        va[1][tg] = MFMA16(xf[tg][ks], b1, va[1][tg]);
      }
    }
    short8 vB[2];
    #pragma unroll
    for (int et = 0; et < 2; ++et) {
      short8 u;
      #pragma unroll
      for (int tg = 0; tg < 2; ++tg)
        #pragma unroll
        for (int r = 0; r < 4; ++r)
          u[tg * 4 + r] = sbf(va[et][tg][r]);
      vB[et] = u;
    }
    // context MFMA (K=32 over paired tokens) + atomic drain
    #pragma unroll
    for (int dt = 0; dt < 2; ++dt)
      #pragma unroll
      for (int et = 0; et < 2; ++et) {
        f32x4 zc = {0.f, 0.f, 0.f, 0.f};
        zc = MFMA16(keA[dt], vB[et], zc);
        #pragma unroll
        for (int r = 0; r < 4; ++r)
          atomicAdd(&cred[h * 1024 + (dt * 16 + g4 * 4 + r) * 32 + et * 16 + t16], zc[r]);
      }
  }

  __syncthreads();
  for (int i = tid; i < 4224; i += 512)
    CpAll[(size_t)blockIdx.x * 4224 + i] = cred[i];
}

// ---------------------------------------------------------------- K2:
// reduce 256 block-partials (4224 each) in 8 chunks of 32. (proven)
__global__ __launch_bounds__(256) void k3a_reduce(const float* __restrict__ CpAll,
                                                  float* __restrict__ Cpp) {
  __shared__ float red[256];
  const int t = threadIdx.x;
  const int eg = blockIdx.x;   // 0..32
  const int ch = blockIdx.y;   // 0..7
  const int e = eg * 128 + (t & 127);
  const int half = t >> 7;
  float s = 0.f;
  for (int bb = 0; bb < 16; ++bb) {
    const int b = ch * 32 + half * 16 + bb;
    s += CpAll[(size_t)b * 4224 + e];
  }
  red[t] = s;
  __syncthreads();
  if (t < 128) Cpp[ch * 4224 + eg * 128 + t] = red[t] + red[t + 128];
}

// ---------------------------------------------------------------- K3:
// 8 blocks x 256 thr. Each block: redundant final reduce + mem-kv -> LDS ctxs
// (numerators + denominators), then its 1/8 of the W2 fold (divide+SCALE
// folded) -> W2p packed frag-linear bf16. (r5 P2b/P2c math, proven)
__global__ __launch_bounds__(256) void k3_ctx_fold(const float* __restrict__ Cpp,
                                                   const float* __restrict__ mem_kv,
                                                   const float* __restrict__ w_out,
                                                   unsigned short* __restrict__ W2p) {
  __shared__ float ctxs[4224];
  const int t = threadIdx.x;
  for (int e = t; e < 4224; e += 256) {
    float s = 0.f;
    #pragma unroll
    for (int c = 0; c < 8; ++c) s += Cpp[c * 4224 + e];
    if (e < 4096) {
      const int hh = e >> 10, d = (e >> 5) & 31, ev = e & 31;
      #pragma unroll
      for (int m = 0; m < 4; ++m)
        s += __expf(mem_kv[(hh * 32 + d) * 4 + m]) * mem_kv[512 + (hh * 32 + ev) * 4 + m];
    } else {
      const int si = e - 4096;
      const int hh = si >> 5, d = si & 31;
      #pragma unroll
      for (int m = 0; m < 4; ++m) s += __expf(mem_kv[(hh * 32 + d) * 4 + m]);
    }
    ctxs[e] = s;
  }
  __syncthreads();

  const int gid = blockIdx.x * 256 + t;    // 0..2047
  const int ln2 = gid & 63, frag = gid >> 6;
  const int h = frag & 3, ot = frag >> 2;
  const int o = ot * 16 + (ln2 & 15);
  float wrow[32];
  #pragma unroll
  for (int e = 0; e < 32; ++e) wrow[e] = w_out[o * 128 + h * 32 + e];
  short8 o8;
  #pragma unroll
  for (int j = 0; j < 8; ++j) {
    const int d = (j >> 2) * 16 + ((ln2 >> 4) << 2) + (j & 3);
    float s = 0.f;
    #pragma unroll
    for (int e = 0; e < 32; ++e)
      s += wrow[e] * ctxs[h * 1024 + d * 32 + e];
    o8[j] = sbf(s / ctxs[4096 + h * 32 + d] * SCALE_F);
  }
  *reinterpret_cast<short8*>(W2p + gid * 8) = o8;
}

// ---------------------------------------------------------------- K4:
// 512 blocks x 256 threads (4 waves); wave owns 32 tokens. ROLLED h-loop:
// per head, q GEMM -> softmax over d -> paired B-frag -> W2 partial into z.
// Then bias + rmsnorm -> y. (r4 k5 math, loop-restructured)
__global__ __launch_bounds__(256) void k5_out(const unsigned short* __restrict__ xn,
                                              const unsigned short* __restrict__ Wqp,
                                              const unsigned short* __restrict__ W2p,
                                              const float* __restrict__ b_out,
                                              const float* __restrict__ gamma2,
                                              float* __restrict__ y) {
  const int tid = threadIdx.x, wv = tid >> 6, ln = tid & 63;
  const int g4 = ln >> 4, t16 = ln & 15;
  const int n0 = (blockIdx.x * 4 + wv) * 32;

  // x B-frags (lane: c = ks*32+g4*8+j, token = tg*16+t16)
  short8 xf[2][4];
  #pragma unroll
  for (int tg = 0; tg < 2; ++tg)
    #pragma unroll
    for (int ks = 0; ks < 4; ++ks)
      xf[tg][ks] = *reinterpret_cast<const short8*>(
          xn + (size_t)(n0 + tg * 16 + t16) * 128 + ks * 32 + g4 * 8);

  f32x4 z[8][2] = {};
  #pragma unroll 1
  for (int h = 0; h < 4; ++h) {
    const unsigned short* wq = Wqp + h * 4096;
    // q GEMM: lane: hd = h*32 + rtl*16 + g4*4 + r, tok = tg*16+t16
    f32x4 qa[2][2] = {};
    #pragma unroll
    for (int ks = 0; ks < 4; ++ks) {
      const short8 a0 = *reinterpret_cast<const short8*>(wq + ks * 512 + ln * 8);
      const short8 a1 = *reinterpret_cast<const short8*>(wq + 2048 + ks * 512 + ln * 8);
      #pragma unroll
      for (int tg = 0; tg < 2; ++tg) {
        qa[0][tg] = MFMA16(a0, xf[tg][ks], qa[0][tg]);
        qa[1][tg] = MFMA16(a1, xf[tg][ks], qa[1][tg]);
      }
    }
    // softmax over d -> paired B-frag (slot j: hd = h*32+(j>>2)*16+g4*4+(j&3))
    short8 qBl[2];
    #pragma unroll
    for (int tg = 0; tg < 2; ++tg) {
      float ev[2][4];
      float ss = 0.f;
      #pragma unroll
      for (int rtl = 0; rtl < 2; ++rtl)
        #pragma unroll
        for (int r = 0; r < 4; ++r) {
          ev[rtl][r] = __expf(qa[rtl][tg][r]);
          ss += ev[rtl][r];
        }
      ss += __shfl_xor(ss, 16, 64);
      ss += __shfl_xor(ss, 32, 64);
      const float inv = 1.0f / ss;
      short8 u;
      #pragma unroll
      for (int rtl = 0; rtl < 2; ++rtl)
        #pragma unroll
        for (int r = 0; r < 4; ++r)
          u[rtl * 4 + r] = sbf(ev[rtl][r] * inv);
      qBl[tg] = u;
    }
    // W2 partial: z[ot][tg] += W2frag(ot, h) x qBl[tg]
    #pragma unroll
    for (int ot = 0; ot < 8; ++ot) {
      const short8 a = *reinterpret_cast<const short8*>(W2p + ((ot * 4 + h) * 64 + ln) * 8);
      #pragma unroll
      for (int tg = 0; tg < 2; ++tg)
        z[ot][tg] = MFMA16(a, qBl[tg], z[ot][tg]);
    }
  }

  // + bias, rmsnorm over channels, store
  float ssq[2] = {0.f, 0.f};
  #pragma unroll
  for (int ot = 0; ot < 8; ++ot) {
    const float4 bb = *reinterpret_cast<const float4*>(b_out + ot * 16 + g4 * 4);
    const float barr[4] = {bb.x, bb.y, bb.z, bb.w};
    #pragma unroll
    for (int tg = 0; tg < 2; ++tg)
      #pragma unroll
      for (int r = 0; r < 4; ++r) {
        const float zb = z[ot][tg][r] + barr[r];
        z[ot][tg][r] = zb;
        ssq[tg] += zb * zb;
      }
  }
  float rr[2];
  #pragma unroll
  for (int tg = 0; tg < 2; ++tg) {
    float s = ssq[tg];
    s += __shfl_xor(s, 16, 64);
    s += __shfl_xor(s, 32, 64);
    rr[tg] = rsqrtf(s);
  }
  #pragma unroll
  for (int ot = 0; ot < 8; ++ot) {
    const float4 gg = *reinterpret_cast<const float4*>(gamma2 + ot * 16 + g4 * 4);
    const float garr[4] = {gg.x, gg.y, gg.z, gg.w};
    #pragma unroll
    for (int tg = 0; tg < 2; ++tg)
      #pragma unroll
      for (int r = 0; r < 4; ++r) {
        const int row = ot * 16 + g4 * 4 + r;
        y[(size_t)row * NTOK + n0 + tg * 16 + t16] =
            z[ot][tg][r] * rr[tg] * (garr[r] + 1.0f) * NORM_SCALE_F;
      }
  }
}

// ---------------------------------------------------------------------------
extern "C" void kernel_launch(void* const* d_in, const int* in_sizes, int n_in,
                              void* d_out, int out_size, void* d_ws, size_t ws_size,
                              hipStream_t stream) {
  const float* x      = (const float*)d_in[0];
  const float* gamma1 = (const float*)d_in[1];
  const float* w_qkv  = (const float*)d_in[2];
  const float* mem_kv = (const float*)d_in[3];
  const float* w_out  = (const float*)d_in[4];
  const float* b_out  = (const float*)d_in[5];
  const float* gamma2 = (const float*)d_in[6];
  float* out = (float*)d_out;
  float* ws  = (float*)d_ws;

  // ws layout (float slots), total ~21.4 MB:
  //   [0, 24576)            Wall: packed q/k/v weights (49152 ushorts)
  //   [24576, 32768)        W2p (16384 ushorts)
  //   [32768, 1114112)      CpAll 256*4224
  //   [1114112, 1147904)    Cpp 8*4224
  //   [1147904, 5342208)    xn 65536*128 bf16 (8388608 ushorts)
  unsigned short* Wall = (unsigned short*)ws;    // Wqp | Wkp | Wvp
  unsigned short* Wqp = Wall;
  unsigned short* Wkp = Wall + 16384;
  unsigned short* Wvp = Wall + 32768;
  unsigned short* W2p = (unsigned short*)(ws + 24576);
  float* CpAll = ws + 32768;
  float* Cpp   = CpAll + 1081344;
  unsigned short* xn = (unsigned short*)(ws + 1147904);

  hipLaunchKernelGGL(k0_norm_pack, dim3(1027),   dim3(256), 0, stream, x, w_qkv, gamma1, xn, Wall);
  hipLaunchKernelGGL(k1_kv,        dim3(256),    dim3(512), 0, stream, xn, Wkp, Wvp, CpAll);
  hipLaunchKernelGGL(k3a_reduce,   dim3(33, 8),  dim3(256), 0, stream, CpAll, Cpp);
  hipLaunchKernelGGL(k3_ctx_fold,  dim3(8),      dim3(256), 0, stream, Cpp, mem_kv, w_out, W2p);
  hipLaunchKernelGGL(k5_out,       dim3(512),    dim3(256), 0, stream, xn, Wqp, W2p, b_out, gamma2, out);
}